// Round 13
// baseline (912.715 us; speedup 1.0000x reference)
//
#include <hip/hip_runtime.h>

#define NB_ 16
#define TQ_ 2048
#define TS_ 2048
#define DH_ 1024
#define QB_ 32
#define SB_ 512
#define NT_ 512

typedef _Float16 f16x8 __attribute__((ext_vector_type(8)));
typedef _Float16 f16x4 __attribute__((ext_vector_type(4)));
typedef float f32x4 __attribute__((ext_vector_type(4)));
typedef uint32_t u32x2 __attribute__((ext_vector_type(2)));

// LDS-domain barrier: does NOT drain vmcnt; in-flight global loads survive.
#define LDS_BARRIER() asm volatile("s_waitcnt lgkmcnt(0)\n\ts_barrier" ::: "memory")

__device__ inline uint32_t pack_h2(float a, float b) {
  union { _Float16 h[2]; uint32_t u; } c;
  c.h[0] = (_Float16)a; c.h[1] = (_Float16)b;
  return c.u;
}

__global__ void convert_f32_f16(const float* __restrict__ src, _Float16* __restrict__ dst) {
  size_t i = ((size_t)blockIdx.x * blockDim.x + threadIdx.x) * 8;
  float4 v0 = *(const float4*)(src + i);
  float4 v1 = *(const float4*)(src + i + 4);
  f16x8 o;
  o[0] = (_Float16)v0.x; o[1] = (_Float16)v0.y; o[2] = (_Float16)v0.z; o[3] = (_Float16)v0.w;
  o[4] = (_Float16)v1.x; o[5] = (_Float16)v1.y; o[6] = (_Float16)v1.z; o[7] = (_Float16)v1.w;
  *(f16x8*)(dst + i) = o;
}

template<bool WS16>
__device__ inline f16x8 ld8(const _Float16* __restrict__ hp, const float* __restrict__ fp, size_t idx) {
  if constexpr (WS16) {
    return *(const f16x8*)(hp + idx);
  } else {
    float4 a = *(const float4*)(fp + idx);
    float4 b = *(const float4*)(fp + idx + 4);
    f16x8 t;
    t[0] = (_Float16)a.x; t[1] = (_Float16)a.y; t[2] = (_Float16)a.z; t[3] = (_Float16)a.w;
    t[4] = (_Float16)b.x; t[5] = (_Float16)b.y; t[6] = (_Float16)b.z; t[7] = (_Float16)b.w;
    return t;
  }
}

// LDS layout (bytes), total 133760 (1 WG/CU):
//   q_base : 0      .. 65536   Q [32 q][1024 d] f16, byte=(q*2048+d*2)^((q&7)<<4)  [v8/v12-verified]
//   p_lds  : 65536  .. 98304   P [32 q][512 s] f16, byte=(q*1024+s*2)^((q&7)<<4)
//   vt     : 98304  .. 131072  8 x 4096 per-wave V-transpose [64 h][32 s]  [v6/v12-verified]
//   pmax   : 131072 .. 132096  [8 w][32 q] f32 per-wave partial max
//   lsum   : 132096 .. 133120  [8 w][32 q] f32 per-wave partial sum
//   mst    : 133120 .. 133376  [2][32] f32 running max (tile-parity double-buffered)
//   lst    : 133376 .. 133632  [2][32] f32 running sum (tile-parity double-buffered)
//   c_lds  : 133632 .. 133760  [32] f32 per-tile rescale factor
template<bool WS16>
__global__ __launch_bounds__(NT_, 2)
void attn_v13(const float* __restrict__ hid,
              const float* __restrict__ enc,
              const _Float16* __restrict__ encH,
              float* __restrict__ out) {
  __shared__ __attribute__((aligned(16))) char smem[133760];
  char*  const q_base = smem;
  char*  const p_lds  = smem + 65536;
  char*  const vt_all = smem + 98304;
  float* const pmax   = (float*)(smem + 131072);
  float* const lsum   = (float*)(smem + 132096);
  float* const mst    = (float*)(smem + 133120);   // [2][32]
  float* const lst    = (float*)(smem + 133376);   // [2][32]
  float* const c_lds  = (float*)(smem + 133632);

  const int tid  = threadIdx.x;
  const int lane = tid & 63;
  const int wid  = tid >> 6;
  const int arow = lane & 15;
  const int agrp = lane >> 4;

  // XCD-affine: XCD x sweeps all 64 q-tiles of batch x, then batch x+8.
  const int bi  = blockIdx.x;
  const int x   = bi & 7;
  const int idx = bi >> 3;
  const int b   = x + 8 * (idx >> 6);
  const int q0  = (idx & 63) * QB_;

  const int hw = wid;   // PV h-chunk (128 wide); QK^T s-slice = wid*64

  if (tid < 32) { mst[tid] = -__builtin_inff(); lst[tid] = 0.0f; }

  // ---- stage Q (32 x 1024) fp32 -> f16 into LDS, swizzled (verified) ----
  {
    const float* qsrc = hid + ((size_t)b * TQ_ + q0) * DH_;
    #pragma unroll
    for (int k = 0; k < 16; ++k) {
      int i = tid + k * NT_;
      int q = i >> 8;
      int h = (i & 255) * 4;
      float4 v = *(const float4*)(qsrc + (size_t)q * DH_ + h);
      int byte = (q * 2048 + h * 2) ^ ((q & 7) << 4);
      *(uint32_t*)(q_base + byte)     = pack_h2(v.x, v.y);
      *(uint32_t*)(q_base + byte + 4) = pack_h2(v.z, v.w);
    }
  }
  __syncthreads();

  f32x4 o_acc[2][8];   // [m][r*4+n] over 128 h  (64 AGPR persistent)
  #pragma unroll
  for (int m = 0; m < 2; ++m)
    #pragma unroll
    for (int n = 0; n < 8; ++n)
      o_acc[m][n] = {};

  char* const vt = vt_all + wid * 4096;
  const size_t enc_b = (size_t)b * TS_ * DH_;
  const int c8 = (lane & 7) * 8;        // V staging h-octet (within 64)
  const int d2 = (lane >> 3) * 2;       // V staging s-pair base

  for (int st = 0; st < TS_ / SB_; ++st) {
    const int s0 = st * SB_;
    const int p  = st & 1;

    // ================= swapped QK^T: C[s][q], wave s-slice = wid*64 =================
    f32x4 sacc[4][2];   // [t s-subtile][m q-subtile]
    #pragma unroll
    for (int t = 0; t < 4; ++t) { sacc[t][0] = {}; sacc[t][1] = {}; }
    {
      const size_t krow = enc_b + (size_t)(s0 + wid * 64 + arow) * DH_;
      #pragma unroll
      for (int kf = 0; kf < 32; ++kf) {
        const int d = kf * 32 + agrp * 8;
        f16x8 qf0 = *(const f16x8*)(q_base + ((arow * 2048 + d * 2) ^ ((arow & 7) << 4)));
        f16x8 qf1 = *(const f16x8*)(q_base + (((16 + arow) * 2048 + d * 2) ^ ((arow & 7) << 4)));
        #pragma unroll
        for (int t = 0; t < 4; ++t) {
          f16x8 kfr = ld8<WS16>(encH, enc, krow + (size_t)(t * 16) * DH_ + d);
          sacc[t][0] = __builtin_amdgcn_mfma_f32_16x16x32_f16(kfr, qf0, sacc[t][0], 0, 0, 0);
          sacc[t][1] = __builtin_amdgcn_mfma_f32_16x16x32_f16(kfr, qf1, sacc[t][1], 0, 0, 0);
        }
      }
    }

    // ---- issue PV pass-0 V loads (fly across both barriers) ----
    f16x8 stgA[2][2], stgB[2][2];
    #pragma unroll
    for (int it = 0; it < 2; ++it) {
      size_t base = enc_b + (size_t)(s0 + it * 16 + d2) * DH_ + hw * 128 + c8;
      stgA[it][0] = ld8<WS16>(encH, enc, base);
      stgA[it][1] = ld8<WS16>(encH, enc, base + DH_);
    }

    // ================= in-register online softmax =================
    float mprev[2], mnew[2];
    // per-wave partial max for q = m*16+arow over wave's 64 s
    #pragma unroll
    for (int m = 0; m < 2; ++m) {
      float pm = sacc[0][m][0];
      #pragma unroll
      for (int t = 0; t < 4; ++t)
        #pragma unroll
        for (int i2 = 0; i2 < 4; ++i2) pm = fmaxf(pm, sacc[t][m][i2]);
      pm = fmaxf(pm, __shfl_xor(pm, 16));
      pm = fmaxf(pm, __shfl_xor(pm, 32));
      if (agrp == 0) pmax[wid * 32 + m * 16 + arow] = pm;
    }

    LDS_BARRIER();  // b1: pmax complete

    #pragma unroll
    for (int m = 0; m < 2; ++m) {
      const int q = m * 16 + arow;
      float mv = mst[p * 32 + q];
      mprev[m] = mv;
      #pragma unroll
      for (int w = 0; w < 8; ++w) mv = fmaxf(mv, pmax[w * 32 + q]);
      mnew[m] = mv;
    }

    // exp, partial sums, pack P -> LDS (A-frag layout)
    #pragma unroll
    for (int m = 0; m < 2; ++m) {
      const int q = m * 16 + arow;
      float ls = 0.0f;
      #pragma unroll
      for (int t = 0; t < 4; ++t) {
        float e0 = __expf(sacc[t][m][0] - mnew[m]);
        float e1 = __expf(sacc[t][m][1] - mnew[m]);
        float e2 = __expf(sacc[t][m][2] - mnew[m]);
        float e3 = __expf(sacc[t][m][3] - mnew[m]);
        ls += (e0 + e1) + (e2 + e3);
        u32x2 pw;
        pw[0] = pack_h2(e0, e1);
        pw[1] = pack_h2(e2, e3);
        const int s_loc = wid * 64 + t * 16 + agrp * 4;
        *(u32x2*)(p_lds + ((q * 1024 + s_loc * 2) ^ ((arow & 7) << 4))) = pw;
      }
      ls += __shfl_xor(ls, 16);
      ls += __shfl_xor(ls, 32);
      if (agrp == 0) lsum[wid * 32 + q] = ls;
    }

    // wave 0 publishes rescale factor + next max state (pre-b2)
    if (wid == 0 && agrp == 0) {
      #pragma unroll
      for (int m = 0; m < 2; ++m) {
        const int q = m * 16 + arow;
        c_lds[q] = __expf(mprev[m] - mnew[m]);
        mst[(p ^ 1) * 32 + q] = mnew[m];
      }
    }

    LDS_BARRIER();  // b2: P + lsum + c complete

    // l update (post-b2, wave 0) — read next tile / epilogue only
    if (wid == 0 && agrp == 0) {
      #pragma unroll
      for (int m = 0; m < 2; ++m) {
        const int q = m * 16 + arow;
        float s8 = 0.0f;
        #pragma unroll
        for (int w = 0; w < 8; ++w) s8 += lsum[w * 32 + q];
        lst[(p ^ 1) * 32 + q] = lst[p * 32 + q] * c_lds[q] + s8;
      }
    }

    // ---- rescale O ----
    #pragma unroll
    for (int m = 0; m < 2; ++m)
      #pragma unroll
      for (int i2 = 0; i2 < 4; ++i2) {
        float cf = c_lds[m * 16 + agrp * 4 + i2];
        #pragma unroll
        for (int n = 0; n < 8; ++n) o_acc[m][n][i2] *= cf;
      }

    // ================= PV: 32 passes (h-round r = pass>>4, s-phase sp = pass&15) =================
    #pragma unroll
    for (int pass = 0; pass < 32; ++pass) {
      const int r  = pass >> 4, sp = pass & 15;
      const bool useA = (pass & 1) == 0;
      // write Vt from current buffer (wave-private, DS in-order, no barrier)
      #pragma unroll
      for (int it = 0; it < 2; ++it) {
        int sl = it * 16 + d2;
        #pragma unroll
        for (int jj = 0; jj < 8; ++jj) {
          int hl = c8 + jj;
          union { _Float16 h[2]; uint32_t u; } pk;
          pk.h[0] = useA ? stgA[it][0][jj] : stgB[it][0][jj];
          pk.h[1] = useA ? stgA[it][1][jj] : stgB[it][1][jj];
          *(uint32_t*)(vt + ((hl * 64 + sl * 2) ^ (((hl >> 3) & 7) << 4))) = pk.u;
        }
      }
      // issue next pass's V loads into the other buffer
      if (pass < 31) {
        const int rn = (pass + 1) >> 4, spn = (pass + 1) & 15;
        #pragma unroll
        for (int it = 0; it < 2; ++it) {
          size_t base = enc_b + (size_t)(s0 + spn * 32 + it * 16 + d2) * DH_
                        + hw * 128 + rn * 64 + c8;
          if (useA) {
            stgB[it][0] = ld8<WS16>(encH, enc, base);
            stgB[it][1] = ld8<WS16>(encH, enc, base + DH_);
          } else {
            stgA[it][0] = ld8<WS16>(encH, enc, base);
            stgA[it][1] = ld8<WS16>(encH, enc, base + DH_);
          }
        }
      }
      // P A-frags for this s-phase
      f16x8 paf0 = *(const f16x8*)(p_lds +
          ((arow * 1024 + sp * 64 + agrp * 16) ^ ((arow & 7) << 4)));
      f16x8 paf1 = *(const f16x8*)(p_lds +
          (((16 + arow) * 1024 + sp * 64 + agrp * 16) ^ ((arow & 7) << 4)));
      __builtin_amdgcn_s_setprio(1);
      #pragma unroll
      for (int n = 0; n < 4; ++n) {
        int hl = n * 16 + arow;
        f16x8 bv = *(const f16x8*)(vt + ((hl * 64 + agrp * 16) ^ (((hl >> 3) & 7) << 4)));
        o_acc[0][r * 4 + n] = __builtin_amdgcn_mfma_f32_16x16x32_f16(paf0, bv, o_acc[0][r * 4 + n], 0, 0, 0);
        o_acc[1][r * 4 + n] = __builtin_amdgcn_mfma_f32_16x16x32_f16(paf1, bv, o_acc[1][r * 4 + n], 0, 0, 0);
      }
      __builtin_amdgcn_s_setprio(0);
    }
  }

  LDS_BARRIER();  // final l state (slot 0 after 4 tiles) visible to all

  // ================= epilogue: O / l =================
  #pragma unroll
  for (int m = 0; m < 2; ++m) {
    #pragma unroll
    for (int i2 = 0; i2 < 4; ++i2) {
      int qr = m * 16 + agrp * 4 + i2;
      float inv = 1.0f / lst[qr];   // slot 0
      #pragma unroll
      for (int n = 0; n < 8; ++n) {
        out[((size_t)(b * TQ_ + q0 + qr)) * DH_ + hw * 128 + (n >> 2) * 64 + (n & 3) * 16 + arow] =
            o_acc[m][n][i2] * inv;
      }
    }
  }
}

extern "C" void kernel_launch(void* const* d_in, const int* in_sizes, int n_in,
                              void* d_out, int out_size, void* d_ws, size_t ws_size,
                              hipStream_t stream) {
  (void)in_sizes; (void)n_in; (void)out_size;
  const float* hid = (const float*)d_in[0];
  const float* enc = (const float*)d_in[1];
  float* out = (float*)d_out;

  const size_t encN = (size_t)NB_ * TS_ * DH_;
  const bool ws16 = (ws_size >= encN * sizeof(_Float16));

  dim3 grid(NB_ * (TQ_ / QB_), 1, 1);
  dim3 block(NT_, 1, 1);

  if (ws16) {
    _Float16* encH = (_Float16*)d_ws;
    convert_f32_f16<<<dim3((unsigned)(encN / 8 / 256)), dim3(256), 0, stream>>>(enc, encH);
    attn_v13<true><<<grid, block, 0, stream>>>(hid, enc, encH, out);
  } else {
    attn_v13<false><<<grid, block, 0, stream>>>(hid, enc, nullptr, out);
  }
}